// Round 8
// baseline (437.841 us; speedup 1.0000x reference)
//
#include <hip/hip_runtime.h>
#include <math.h>

// ---------------- problem dims ----------------
#define NB 32
#define NT 64
#define NF 2048  // NB*NT frames

// ---------------- output float offsets ----------------
#define OUT_ZS    2097152
#define OUT_PRM   (OUT_ZS + 65536)
#define OUT_PRLS  (OUT_PRM + 65536)
#define OUT_PM    (OUT_PRLS + 65536)
#define OUT_PLS   (OUT_PM + 65536)
#define OUT_HF    (OUT_PLS + 65536)

// ---------------- workspace float offsets ----------------
#define WS_HS    27394048   // 64*32*128
#define WS_ENCT  27656192   // enc_pw^T (1024x64)
#define WS_WP1H  27885568   // 128x128 f16
#define WS_WP2   27893760   // 128x128 f16
#define WS_WP3   27901952   // 64x128 f16
#define WS_WWHH  27906048   // 384x128 f16
#define WS_WIHZ  27930624   // 384x32 f16
#define WS_PW1T  27977984   // 192x128
#define WS_WIHT  28002560   // 34x384
#define WS_WC2   16777216   // 16*64*32 bf16
#define WS_WC3   (WS_WC2 + 16384)
#define WS_WD1   (WS_WC3 + 32768)
#define WS_WD2   (WS_WD1 + 32768)
#define WS_DLIN  16908288   // 2048x1024 bf16 (declin output)
#define WS_DECWF 17960960   // 1024x160 f16 (dec_pw rows)
#define WS_QW1F  18045952   // 128x160 f16 (pri_w1 padded 130->160)
#define WS_QW2F  18057216   // 128x128 f16
#define WS_QW3F  18066432   // 64x128 f16
#define WS_POSL1E 25165824  // 2048*128
#define WS_GIA    (WS_POSL1E + 262144)  // 2048*384

// ==================== helpers ====================
typedef __attribute__((ext_vector_type(8))) short short8;
typedef __attribute__((ext_vector_type(4))) float floatx4;
typedef _Float16 __attribute__((ext_vector_type(2))) half2v;
typedef _Float16 __attribute__((ext_vector_type(8))) half8;
union U4S8 { uint4 u; short8 s; };
__device__ __forceinline__ short8 u2s(uint4 u) { U4S8 x; x.u = u; return x.s; }
union U4HH { uint4 u; half8 h; };
__device__ __forceinline__ half8 u2hh(uint4 u) { U4HH x; x.u = u; return x.h; }

__device__ __forceinline__ float rcpf(float x) {
#if __has_builtin(__builtin_amdgcn_rcpf)
  return __builtin_amdgcn_rcpf(x);
#else
  return 1.f / x;
#endif
}
__device__ __forceinline__ float eluf(float a) {
  return (a > 0.f) ? a : (__expf(a) - 1.f);
}
__device__ __forceinline__ float sigm(float a) {
  return rcpf(1.f + __expf(-a));
}
__device__ __forceinline__ float tanhfast(float x) {
  const float e = __expf(fminf(-2.f * x, 60.f));
  return (1.f - e) * rcpf(1.f + e);
}
__device__ __forceinline__ unsigned short f2bf(float f) {
  unsigned int u = __float_as_uint(f);
  u += 0x7fffu + ((u >> 16) & 1u);
  return (unsigned short)(u >> 16);
}
__device__ __forceinline__ unsigned short f2h(float f) {
  _Float16 h = (_Float16)f;
  return __builtin_bit_cast(unsigned short, h);
}
__device__ __forceinline__ unsigned int pack2h(float a, float b) {
  return (unsigned int)f2h(a) | ((unsigned int)f2h(b) << 16);
}
union UH2 { unsigned int u; half2v h; };
__device__ __forceinline__ half2v u2h(unsigned int u) { UH2 x; x.u = u; return x.h; }

__device__ __forceinline__ float fdot2w(half2v a, half2v b, float c) {
#if __has_builtin(__builtin_amdgcn_fdot2)
  return __builtin_amdgcn_fdot2(a, b, c, false);
#else
  return fmaf((float)a[0], (float)b[0], fmaf((float)a[1], (float)b[1], c));
#endif
}

// f16-pair dot: 8 MACs via 4 v_dot2_f32_f16 into 4 independent accumulators.
union U4H2 { uint4 u; half2v h[4]; };
__device__ __forceinline__ void dot8h(uint4 w, uint4 x,
                                      float& a0, float& a1, float& a2, float& a3) {
  U4H2 W; W.u = w;
  U4H2 X; X.u = x;
  a0 = fdot2w(W.h[0], X.h[0], a0);
  a1 = fdot2w(W.h[1], X.h[1], a1);
  a2 = fdot2w(W.h[2], X.h[2], a2);
  a3 = fdot2w(W.h[3], X.h[3], a3);
}

// ==================== unified prep: fp32 transposes + f16/bf16 packs =======
// mode 10: fp32 transpose dst[c*A+r]=src[r*B+c]
// mode 0: f16 direct; 1: pos_w1 h-part (f16); 2: wih z-part (f16);
// mode 3: conv w [oc][ic][t]->[t][oc][ic] (bf16); 4: deconv w (bf16)
// mode 6: pri_w1 pad K 130->160 (f16)
struct PP { const float* src; void* dst; int n; int mode; int A; int B; };
struct PPAll { PP m[16]; };

__global__ __launch_bounds__(256) void k_prep(PPAll a) {
  PP p = a.m[blockIdx.y];
  for (int i = blockIdx.x * 256 + threadIdx.x; i < p.n; i += gridDim.x * 256) {
    if (p.mode == 10) {
      const int r = i / p.B, c = i - r * p.B;
      ((float*)p.dst)[c * p.A + r] = p.src[i];
    } else {
      float v;
      if (p.mode == 0) v = p.src[i];
      else if (p.mode == 1) v = p.src[(i >> 7) * 192 + (i & 127)];
      else if (p.mode == 2) v = p.src[(i >> 5) * 34 + (i & 31)];
      else if (p.mode == 6) {
        const int o = i / 160, k = i - o * 160;
        v = (k < 130) ? p.src[o * 130 + k] : 0.f;
      } else {
        const int ab = p.A * p.B;
        const int t = i / ab, rem = i - t * ab;
        const int oc = rem / p.B, ic = rem - oc * p.B;
        v = (p.mode == 3) ? p.src[(oc * p.B + ic) * 16 + t]
                          : p.src[(ic * p.A + oc) * 16 + t];
      }
      ((unsigned short*)p.dst)[i] = (p.mode <= 2 || p.mode == 6) ? f2h(v) : f2bf(v);
    }
  }
}

// ==================== fused encoder: conv1->conv2->conv3->enclin->pre ======
// one block per frame f = b*64+t ; all activations LDS-resident.
// LDS ~51KB -> 3 blocks/CU.
__global__ __launch_bounds__(256, 3) void k_enc(
    const float* __restrict__ obs, const float* __restrict__ act,
    const float* __restrict__ w1, const float* __restrict__ b1,
    const unsigned short* __restrict__ wc2, const float* __restrict__ b2,
    const unsigned short* __restrict__ wc3, const float* __restrict__ b3,
    const float* __restrict__ encT, const float* __restrict__ encb,
    const float* __restrict__ pw1T, const float* __restrict__ pb1,
    const float* __restrict__ wihT, const float* __restrict__ bih,
    const float* __restrict__ bhh,
    float* __restrict__ posl1e, float* __restrict__ gia) {
  const int f = blockIdx.x, tid = threadIdx.x;
  const int w = tid >> 6, l = tid & 63, q = l >> 4, n = l & 15;
  __shared__ float sIn1[32 * 33];
  __shared__ float sW1[512];
  __shared__ float sB1[32];
  __shared__ __align__(16) unsigned short sIn2[18 * 18 * 40];  // conv2 haloed in
  __shared__ __align__(16) unsigned short sIn3[10 * 10 * 72];  // conv3 haloed in
  __shared__ __align__(16) float sXe[1024];                    // enclin in [ch*16+px]
  __shared__ float sP[256];
  __shared__ float sE[64];
  __shared__ float sA2[2];

  // ---- stage conv1 inputs + zero haloed buffers
  {
    const float* in = obs + (size_t)f * 1024;
    for (int i = tid; i < 1024; i += 256) sIn1[(i >> 5) * 33 + (i & 31)] = in[i];
    for (int i = tid; i < 512; i += 256) sW1[i] = w1[i];
    if (tid < 32) sB1[tid] = b1[tid];
    if (tid < 2) sA2[tid] = act[(size_t)f * 2 + tid];
    unsigned int* z2 = (unsigned int*)sIn2;
    for (int i = tid; i < 18 * 18 * 40 / 2; i += 256) z2[i] = 0u;
    unsigned int* z3 = (unsigned int*)sIn3;
    for (int i = tid; i < 10 * 10 * 72 / 2; i += 256) z3[i] = 0u;
  }
  __syncthreads();
  // ---- conv1 (fp32) -> sIn2 interior
  for (int r = tid; r < 512; r += 256) {       // r = oc*16 + oy
    const int oc = r >> 4, oy = r & 15;
    float acc[16];
    const float bv = sB1[oc];
#pragma unroll
    for (int j = 0; j < 16; j++) acc[j] = bv;
#pragma unroll
    for (int ky = 0; ky < 4; ky++) {
      const int iy = 2 * oy + ky - 1;
      if (iy < 0 || iy >= 32) continue;
#pragma unroll
      for (int kx = 0; kx < 4; kx++) {
        const float wv = sW1[oc * 16 + ky * 4 + kx];
#pragma unroll
        for (int j = 0; j < 16; j++) {
          const int ix = 2 * j + kx - 1;
          if (ix >= 0 && ix < 32) acc[j] += wv * sIn1[iy * 33 + ix];
        }
      }
    }
#pragma unroll
    for (int j = 0; j < 16; j++)
      sIn2[((oy + 1) * 18 + (j + 1)) * 40 + oc] = f2bf(fmaxf(acc[j], 0.f));
  }
  __syncthreads();
  // ---- conv2 MFMA (IC=32 OC=64, 16x16 out) -> sIn3 interior
  {
    int base[4];
#pragma unroll
    for (int nt = 0; nt < 4; nt++) {
      const int px = nt * 16 + n, oy = px >> 3, ox = px & 7;
      base[nt] = ((2 * oy + 1) * 18 + (2 * ox + 1)) * 40 + q * 8;
    }
    floatx4 acc[4];
#pragma unroll
    for (int nt = 0; nt < 4; nt++) acc[nt] = (floatx4){0.f, 0.f, 0.f, 0.f};
    uint4 af[16];
#pragma unroll
    for (int t = 0; t < 16; t++)
      af[t] = *reinterpret_cast<const uint4*>(wc2 + (size_t)(t * 64 + w * 16 + n) * 32 + q * 8);
#pragma unroll
    for (int t = 0; t < 16; t++) {
      const int toff = ((t / 4 - 1) * 18 + (t % 4 - 1)) * 40;
#pragma unroll
      for (int nt = 0; nt < 4; nt++) {
        uint4 bf = *reinterpret_cast<const uint4*>(&sIn2[base[nt] + toff]);
        acc[nt] = __builtin_amdgcn_mfma_f32_16x16x32_bf16(u2s(af[t]), u2s(bf), acc[nt], 0, 0, 0);
      }
    }
    float b4[4];
#pragma unroll
    for (int r = 0; r < 4; r++) b4[r] = b2[w * 16 + q * 4 + r];
    __syncthreads();
#pragma unroll
    for (int nt = 0; nt < 4; nt++) {
      const int px = nt * 16 + n, oy = px >> 3, ox = px & 7;
#pragma unroll
      for (int r = 0; r < 4; r++)
        sIn3[((oy + 1) * 10 + (ox + 1)) * 72 + (w * 16 + q * 4 + r)] =
            f2bf(fmaxf(acc[nt][r] + b4[r], 0.f));
    }
  }
  __syncthreads();
  // ---- conv3 MFMA (IC=64 OC=64, 4x4 out) -> sXe fp32 [ch*16+px]
  {
    const int oy = n >> 2, ox = n & 3;
    const int ibase = ((2 * oy + 1) * 10 + (2 * ox + 1)) * 72 + q * 8;
    floatx4 acc = (floatx4){0.f, 0.f, 0.f, 0.f};
    for (int ks = 0; ks < 2; ks++) {
      uint4 af[16];
#pragma unroll
      for (int t = 0; t < 16; t++)
        af[t] = *reinterpret_cast<const uint4*>(
            wc3 + (size_t)(t * 64 + w * 16 + n) * 64 + ks * 32 + q * 8);
#pragma unroll
      for (int t = 0; t < 16; t++) {
        const int toff = ((t / 4 - 1) * 10 + (t % 4 - 1)) * 72 + ks * 32;
        uint4 bf = *reinterpret_cast<const uint4*>(&sIn3[ibase + toff]);
        acc = __builtin_amdgcn_mfma_f32_16x16x32_bf16(u2s(af[t]), u2s(bf), acc, 0, 0, 0);
      }
    }
#pragma unroll
    for (int r = 0; r < 4; r++) {
      const int ch = w * 16 + q * 4 + r;
      sXe[ch * 16 + n] = fmaxf(acc[r] + b3[ch], 0.f);
    }
  }
  __syncthreads();
  // ---- enclin -> sE[64]
  {
    const int o = tid & 63, s = tid >> 6;
    float acc = 0.f;
    const int k0 = s * 256;
    for (int k = k0; k < k0 + 256; k++) acc += encT[k * 64 + o] * sXe[k];
    sP[tid] = acc;
  }
  __syncthreads();
  if (tid < 64)
    sE[tid] = sP[tid] + sP[tid + 64] + sP[tid + 128] + sP[tid + 192] + encb[tid];
  __syncthreads();
  // ---- pre: posl1e (e-part) + gia (a-part, interleaved [j%128]*3+gate, + bhh)
  if (tid < 128) {
    float a = pb1[tid];
    for (int k = 0; k < 64; k++) a += pw1T[(128 + k) * 128 + tid] * sE[k];
    posl1e[(size_t)f * 128 + tid] = a;
  } else {
#pragma unroll
    for (int jj = 0; jj < 3; jj++) {
      const int j = (tid - 128) + jj * 128;
      gia[(size_t)f * 384 + (tid - 128) * 3 + jj] =
          bih[j] + bhh[j] + wihT[32 * 384 + j] * sA2[0] + wihT[33 * 384 + j] * sA2[1];
    }
  }
}

// ==================== recurrent core (f16 dot2 + shfl reductions) ==========
// 32 blocks x 512 threads. Per step, 4 barriers (round-6 verified structure):
//   A: L1+gh via 4-row/K-quarter amortization (R=tid>>2, ks4=tid&3)
//   B: L2, out=tid>>2, K-quarter=tid&3, shfl_xor combine
//   C: L3 row-paired outputs; shfl_xor(8) pairs pm/pls; z inline
//   FG: gi dots (K=32) + GRU fused on tid<128; h fp32 in register.
// bhh folded into gia (k_enc); gia/sGh interleaved as float3 per h-row.
__global__ __launch_bounds__(512, 2) void k_rssm4(
    const float* __restrict__ posl1e, const float* __restrict__ gia,
    const float* __restrict__ noise,
    const unsigned short* __restrict__ wp1h, const unsigned short* __restrict__ wp2,
    const unsigned short* __restrict__ wp3, const unsigned short* __restrict__ wwhh,
    const unsigned short* __restrict__ wihz,
    const float* __restrict__ pb2, const float* __restrict__ pb3,
    float* __restrict__ hs, float* __restrict__ out) {
  const int b = blockIdx.x, tid = threadIdx.x;
  const int R = tid >> 2, ks4 = tid & 3;
  __shared__ __align__(16) _Float16 sHh[128];
  __shared__ __align__(16) _Float16 sL1h[128];
  __shared__ __align__(16) _Float16 sL2h[128];
  __shared__ __align__(16) _Float16 sZh[32];
  __shared__ float sGh[384];   // interleaved: [R*3 + gate]

  uint4 wA4[4][4];  // j=0: L1 row R; j=1..3: whh rows R,R+128,R+256; K-quarter ks4
  {
#pragma unroll
    for (int j = 0; j < 4; j++) {
      const unsigned short* p = (j == 0)
          ? (wp1h + R * 128)
          : (wwhh + (size_t)((j - 1) * 128 + R) * 128);
      const uint4* pv = reinterpret_cast<const uint4*>(p + ks4 * 32);
#pragma unroll
      for (int i = 0; i < 4; i++) wA4[j][i] = pv[i];
    }
  }
  uint4 wB[4];
  {
    const unsigned short* rowB = wp2 + R * 128 + ks4 * 32;
#pragma unroll
    for (int i = 0; i < 4; i++) wB[i] = reinterpret_cast<const uint4*>(rowB)[i];
  }
  uint4 wC[2];
  {
    // row-paired output mapping: r = tid>>3, o = (r>>1) + 32*(r&1)
    const int r = tid >> 3;
    const int o = (r >> 1) + ((r & 1) << 5);
    const unsigned short* rowC = wp3 + o * 128 + (tid & 7) * 16;
#pragma unroll
    for (int i = 0; i < 2; i++) wC[i] = reinterpret_cast<const uint4*>(rowC)[i];
  }
  uint4 wD[3][4];
  if (tid < 128) {
#pragma unroll
    for (int j = 0; j < 3; j++) {
      const unsigned short* rowD = wihz + (size_t)(tid + 128 * j) * 32;
#pragma unroll
      for (int i = 0; i < 4; i++) wD[j][i] = reinterpret_cast<const uint4*>(rowD)[i];
    }
  }
  const bool zlane = (tid & 15) == 0;   // j = tid>>4
  const int jz = tid >> 4;
  const float pb2R = pb2[R];
  const float pb3mR = zlane ? pb3[jz] : 0.f;
  const float pb3sR = zlane ? pb3[jz + 32] : 0.f;

  float h_reg = 0.f;
  float pl1R = 0.f, epsR = 0.f;
  float3 gaR = {0.f, 0.f, 0.f};
  if (ks4 == 0) pl1R = posl1e[(size_t)(b * 64) * 128 + R];
  if (tid < 128) {
    gaR = *reinterpret_cast<const float3*>(&gia[(size_t)(b * 64) * 384 + tid * 3]);
    sHh[tid] = (_Float16)0.f;
    hs[(size_t)b * 128 + tid] = 0.f;
  }
  if (zlane) epsR = noise[(size_t)b * 32 + jz];
  __syncthreads();

  for (int t = 0; t < 64; ++t) {
    const int tn = (t < 63) ? t + 1 : 63;
    float pl1N = 0.f, epsN = 0.f;
    float3 gaN = {0.f, 0.f, 0.f};
    if (ks4 == 0) pl1N = posl1e[(size_t)(b * 64 + tn) * 128 + R];
    if (tid < 128)
      gaN = *reinterpret_cast<const float3*>(&gia[(size_t)(b * 64 + tn) * 384 + tid * 3]);
    if (zlane) epsN = noise[(size_t)(tn * 32 + b) * 32 + jz];

    // ---- A: L1 + gh (K-quarter per thread, 4 rows)
    {
      const uint4* xs = reinterpret_cast<const uint4*>(sHh) + ks4 * 4;
      const uint4 x0 = xs[0], x1 = xs[1], x2 = xs[2], x3 = xs[3];
      float part[4];
#pragma unroll
      for (int j = 0; j < 4; j++) {
        float p0 = 0.f, p1 = 0.f, p2 = 0.f, p3 = 0.f;
        dot8h(wA4[j][0], x0, p0, p1, p2, p3);
        dot8h(wA4[j][1], x1, p0, p1, p2, p3);
        dot8h(wA4[j][2], x2, p0, p1, p2, p3);
        dot8h(wA4[j][3], x3, p0, p1, p2, p3);
        part[j] = (p0 + p1) + (p2 + p3);
      }
#pragma unroll
      for (int j = 0; j < 4; j++) {
        part[j] += __shfl_xor(part[j], 1);
        part[j] += __shfl_xor(part[j], 2);
      }
      if (ks4 == 0) {
        sL1h[R] = (_Float16)eluf(part[0] + pl1R);
        sGh[R * 3] = part[1];
        sGh[R * 3 + 1] = part[2];
        sGh[R * 3 + 2] = part[3];
      }
    }
    __syncthreads();
    // ---- B: L2 (4-way K-split, in-wave combine)
    {
      float a0 = 0.f, a1 = 0.f, a2 = 0.f, a3 = 0.f;
      const uint4* xs = reinterpret_cast<const uint4*>(sL1h) + ks4 * 4;
#pragma unroll
      for (int i = 0; i < 4; i++) dot8h(wB[i], xs[i], a0, a1, a2, a3);
      float p = (a0 + a1) + (a2 + a3);
      p += __shfl_xor(p, 1);
      p += __shfl_xor(p, 2);
      if (ks4 == 0) sL2h[R] = (_Float16)eluf(p + pb2R);
    }
    __syncthreads();
    // ---- C: L3 (8-way K-split) + in-wave pm/pls pairing + z
    {
      float a0 = 0.f, a1 = 0.f, a2 = 0.f, a3 = 0.f;
      const uint4* xs = reinterpret_cast<const uint4*>(sL2h) + (tid & 7) * 2;
      dot8h(wC[0], xs[0], a0, a1, a2, a3);
      dot8h(wC[1], xs[1], a0, a1, a2, a3);
      float p = (a0 + a1) + (a2 + a3);
      p += __shfl_xor(p, 1);
      p += __shfl_xor(p, 2);
      p += __shfl_xor(p, 4);            // all 8 lanes of row hold total
      const float pq = __shfl_xor(p, 8); // partner row's total (pls row)
      if (zlane) {
        const float pm = p + pb3mR;
        float pls = pq + pb3sR;
        pls = fminf(fmaxf(pls, -5.f), 2.f);
        const float z = pm + __expf(pls) * epsR;
        sZh[jz] = (_Float16)z;
        const int o = (b * 64 + t) * 32 + jz;
        out[OUT_ZS + o] = z;
        out[OUT_PM + o] = pm;
        out[OUT_PLS + o] = pls;
      }
    }
    __syncthreads();
    // ---- FG: gi dots (K=32) + GRU, fused on tid<128
    if (tid < 128) {
      float r0 = 0.f, r1 = 0.f, r2 = 0.f, r3 = 0.f;
      float u0 = 0.f, u1 = 0.f, u2 = 0.f, u3 = 0.f;
      float m0 = 0.f, m1 = 0.f, m2 = 0.f, m3 = 0.f;
      const uint4* xs = reinterpret_cast<const uint4*>(sZh);
#pragma unroll
      for (int i = 0; i < 4; i++) {
        const uint4 xv = xs[i];
        dot8h(wD[0][i], xv, r0, r1, r2, r3);
        dot8h(wD[1][i], xv, u0, u1, u2, u3);
        dot8h(wD[2][i], xv, m0, m1, m2, m3);
      }
      const float gr = gaR.x + ((r0 + r1) + (r2 + r3));
      const float gu = gaR.y + ((u0 + u1) + (u2 + u3));
      const float gn = gaR.z + ((m0 + m1) + (m2 + m3));
      const float ghr = sGh[tid * 3];
      const float ghu = sGh[tid * 3 + 1];
      const float ghn = sGh[tid * 3 + 2];
      const float r = sigm(gr + ghr);
      const float u = sigm(gu + ghu);
      const float n = tanhfast(gn + r * ghn);
      const float hn = (1.f - u) * n + u * h_reg;
      h_reg = hn;
      sHh[tid] = (_Float16)hn;
      if (t < 63) hs[(size_t)((t + 1) * 32 + b) * 128 + tid] = hn;
    }
    pl1R = pl1N;
    gaR = gaN;
    epsR = epsN;
    __syncthreads();
  }
  if (tid < 128) out[OUT_HF + b * 128 + tid] = h_reg;
}

// ==================== post: declin GEMM + prior GEMM chain (one dispatch) ==
// blocks [0,2048): declin (2048x160)@(160x1024) -> DLIN bf16
// blocks [2048,2176): prior 3-layer GEMM chain, 16 frames/block
__global__ __launch_bounds__(256) void k_post(
    const float* __restrict__ hs, const float* __restrict__ zs,
    const unsigned short* __restrict__ decwf, const float* __restrict__ decb,
    unsigned short* __restrict__ dlin,
    const float* __restrict__ act,
    const unsigned short* __restrict__ qw1f, const float* __restrict__ qb1,
    const unsigned short* __restrict__ qw2f, const float* __restrict__ qb2,
    const unsigned short* __restrict__ qw3f, const float* __restrict__ qb3,
    float* __restrict__ out) {
  const int tid = threadIdx.x;
  const int bid = blockIdx.x;
  const int w = tid >> 6, l = tid & 63, q = l >> 4, n = l & 15;
  __shared__ __align__(16) _Float16 sB[16][168];
  __shared__ __align__(16) _Float16 sB2[16][136];

  if (bid < 2048) {
    // ---------------- declin ----------------
    const int otile = bid & 15;
    const int fBase = (bid >> 4) * 16;
    for (int i = tid; i < 2560; i += 256) {
      const int fr = i / 160, k = i - fr * 160;
      const int f = fBase + fr;                    // hs-order: f = t*32+b
      float v;
      if (k < 128) v = hs[(size_t)f * 128 + k];
      else v = zs[(size_t)((f & 31) * 64 + (f >> 5)) * 32 + (k - 128)];
      sB[fr][k] = (_Float16)v;
    }
    __syncthreads();
    const int oB = otile * 64 + w * 16;
    floatx4 acc = (floatx4){0.f, 0.f, 0.f, 0.f};
#pragma unroll
    for (int ks = 0; ks < 5; ks++) {
      uint4 a = *reinterpret_cast<const uint4*>(&decwf[(size_t)(oB + n) * 160 + ks * 32 + q * 8]);
      uint4 bb = *reinterpret_cast<const uint4*>(&sB[n][ks * 32 + q * 8]);
      acc = __builtin_amdgcn_mfma_f32_16x16x32_f16(u2hh(a), u2hh(bb), acc, 0, 0, 0);
    }
    const int o0 = oB + q * 4;
    const int f = fBase + n;
    const unsigned int lo = (unsigned int)f2bf(acc[0] + decb[o0]) |
                            ((unsigned int)f2bf(acc[1] + decb[o0 + 1]) << 16);
    const unsigned int hi = (unsigned int)f2bf(acc[2] + decb[o0 + 2]) |
                            ((unsigned int)f2bf(acc[3] + decb[o0 + 3]) << 16);
    *reinterpret_cast<uint2*>(&dlin[(size_t)f * 1024 + o0]) = make_uint2(lo, hi);
    return;
  }
  // ---------------- prior chain ----------------
  const int fBase = (bid - 2048) * 16;
  for (int i = tid; i < 2560; i += 256) {
    const int fr = i / 160, k = i - fr * 160;
    const int f = fBase + fr;
    float v = 0.f;
    if (k < 128) v = hs[(size_t)f * 128 + k];
    else if (k < 130) v = act[(size_t)((f & 31) * 64 + (f >> 5)) * 2 + (k - 128)];
    sB[fr][k] = (_Float16)v;
  }
  __syncthreads();
  // ---- layer1 (128 outs = 2 groups x 4 waves x 16), K=160
#pragma unroll
  for (int g = 0; g < 2; g++) {
    const int oB = g * 64 + w * 16;
    floatx4 acc = (floatx4){0.f, 0.f, 0.f, 0.f};
#pragma unroll
    for (int ks = 0; ks < 5; ks++) {
      uint4 a = *reinterpret_cast<const uint4*>(&qw1f[(oB + n) * 160 + ks * 32 + q * 8]);
      uint4 bb = *reinterpret_cast<const uint4*>(&sB[n][ks * 32 + q * 8]);
      acc = __builtin_amdgcn_mfma_f32_16x16x32_f16(u2hh(a), u2hh(bb), acc, 0, 0, 0);
    }
    const int o0 = oB + q * 4;
    *reinterpret_cast<unsigned int*>(&sB2[n][o0]) =
        pack2h(eluf(acc[0] + qb1[o0]), eluf(acc[1] + qb1[o0 + 1]));
    *reinterpret_cast<unsigned int*>(&sB2[n][o0 + 2]) =
        pack2h(eluf(acc[2] + qb1[o0 + 2]), eluf(acc[3] + qb1[o0 + 3]));
  }
  __syncthreads();
  // ---- layer2 (128 outs), K=128 -> writes back into sB
#pragma unroll
  for (int g = 0; g < 2; g++) {
    const int oB = g * 64 + w * 16;
    floatx4 acc = (floatx4){0.f, 0.f, 0.f, 0.f};
#pragma unroll
    for (int ks = 0; ks < 4; ks++) {
      uint4 a = *reinterpret_cast<const uint4*>(&qw2f[(oB + n) * 128 + ks * 32 + q * 8]);
      uint4 bb = *reinterpret_cast<const uint4*>(&sB2[n][ks * 32 + q * 8]);
      acc = __builtin_amdgcn_mfma_f32_16x16x32_f16(u2hh(a), u2hh(bb), acc, 0, 0, 0);
    }
    const int o0 = oB + q * 4;
    *reinterpret_cast<unsigned int*>(&sB[n][o0]) =
        pack2h(eluf(acc[0] + qb2[o0]), eluf(acc[1] + qb2[o0 + 1]));
    *reinterpret_cast<unsigned int*>(&sB[n][o0 + 2]) =
        pack2h(eluf(acc[2] + qb2[o0 + 2]), eluf(acc[3] + qb2[o0 + 3]));
  }
  __syncthreads();
  // ---- layer3 (64 outs = 4 waves x 16), K=128
  {
    const int oB = w * 16;
    floatx4 acc = (floatx4){0.f, 0.f, 0.f, 0.f};
#pragma unroll
    for (int ks = 0; ks < 4; ks++) {
      uint4 a = *reinterpret_cast<const uint4*>(&qw3f[(oB + n) * 128 + ks * 32 + q * 8]);
      uint4 bb = *reinterpret_cast<const uint4*>(&sB[n][ks * 32 + q * 8]);
      acc = __builtin_amdgcn_mfma_f32_16x16x32_f16(u2hh(a), u2hh(bb), acc, 0, 0, 0);
    }
    const int o0 = oB + q * 4;
    const int f = fBase + n;
    const int ob = ((f & 31) * 64 + (f >> 5)) * 32;
#pragma unroll
    for (int r = 0; r < 4; r++) {
      const int o = o0 + r;
      const float v = acc[r] + qb3[o];
      if (o < 32) out[OUT_PRM + ob + o] = v;
      else out[OUT_PRLS + ob + o - 32] = fminf(fmaxf(v, -5.f), 2.f);
    }
  }
}

// ==================== fused decoder: deconv1->deconv2->deconv3 =============
// one block per frame f = t*32+b ; declin input pre-computed in DLIN (bf16).
#define D3_ROW 580
#define D3_PX  36
__global__ __launch_bounds__(256, 4) void k_dec(
    const unsigned short* __restrict__ dlin,
    const unsigned short* __restrict__ wd1, const float* __restrict__ db1,
    const unsigned short* __restrict__ wd2, const float* __restrict__ db2,
    const float* __restrict__ w3, const float* __restrict__ b3,
    float* __restrict__ out) {
  const int f = blockIdx.x, tid = threadIdx.x;
  const int w = tid >> 6, l = tid & 63, q = l >> 4, n = l & 15;
  const int t = f >> 5, b = f & 31;
  __shared__ __align__(16) unsigned short sInD1[6 * 6 * 72];    // deconv1 haloed in
  __shared__ __align__(16) unsigned short sInD2[10 * 10 * 72];  // deconv2 haloed in
  __shared__ __align__(16) _Float16 sInD3h[16 * D3_ROW];        // deconv3 in, padded
  __shared__ __align__(16) _Float16 sW3h[16 * 32];              // deconv3 w [tap][ic]

  // ---- issue DLIN load early; zero halos; stage deconv3 weights
  const uint2 dv = *reinterpret_cast<const uint2*>(dlin + (size_t)f * 1024 + tid * 4);
  {
    unsigned int* z1 = (unsigned int*)sInD1;
    for (int i = tid; i < 6 * 6 * 72 / 2; i += 256) z1[i] = 0u;
    unsigned int* z2 = (unsigned int*)sInD2;
    for (int i = tid; i < 10 * 10 * 72 / 2; i += 256) z2[i] = 0u;
    for (int s = tid; s < 512; s += 256) {
      const int tap = s >> 5, icc = s & 31;
      sW3h[s] = (_Float16)w3[icc * 16 + tap];
    }
  }
  __syncthreads();
  // ---- scatter DLIN (o = tid*4..+3) into sInD1 halo interior
  {
    const int o0 = tid * 4, c = o0 >> 4, px0 = o0 & 15;
    const int Y = px0 >> 2;
    const int base = ((Y + 1) * 6 + 1) * 72 + c;
    sInD1[base] = (unsigned short)(dv.x & 0xffffu);
    sInD1[base + 72] = (unsigned short)(dv.x >> 16);
    sInD1[base + 144] = (unsigned short)(dv.y & 0xffffu);
    sInD1[base + 216] = (unsigned short)(dv.y >> 16);
  }
  __syncthreads();
  // ---- deconv1 MFMA (IC=64 IH=IW=4 OC=64) -> sInD2 interior
  {
    const int Y = n >> 2, X = n & 3;
    const int ibase = ((Y + 1) * 6 + (X + 1)) * 72 + q * 8;
    float b4[4];
#pragma unroll
    for (int r = 0; r < 4; r++) b4[r] = db1[w * 16 + q * 4 + r];
#pragma unroll
    for (int c = 0; c < 4; c++) {
      const int cy = c >> 1, cx = c & 1;
      floatx4 acc = (floatx4){0.f, 0.f, 0.f, 0.f};
      for (int ks = 0; ks < 2; ks++) {
        uint4 af[4];
#pragma unroll
        for (int tt = 0; tt < 4; tt++) {
          const int t2 = tt >> 1, t3 = tt & 1;
          const int ky = ((cy + 1) & 1) + 2 * t2, kx = ((cx + 1) & 1) + 2 * t3;
          af[tt] = *reinterpret_cast<const uint4*>(
              wd1 + (size_t)((ky * 4 + kx) * 64 + w * 16 + n) * 64 + ks * 32 + q * 8);
        }
#pragma unroll
        for (int tt = 0; tt < 4; tt++) {
          const int t2 = tt >> 1, t3 = tt & 1;
          const int toff = ((cy - t2) * 6 + (cx - t3)) * 72 + ks * 32;
          uint4 bf = *reinterpret_cast<const uint4*>(&sInD1[ibase + toff]);
          acc = __builtin_amdgcn_mfma_f32_16x16x32_bf16(u2s(af[tt]), u2s(bf), acc, 0, 0, 0);
        }
      }
      const int oy = 2 * Y + cy, ox = 2 * X + cx;
#pragma unroll
      for (int r = 0; r < 4; r++)
        sInD2[((oy + 1) * 10 + (ox + 1)) * 72 + (w * 16 + q * 4 + r)] =
            f2bf(fmaxf(acc[r] + b4[r], 0.f));
    }
  }
  __syncthreads();
  // ---- deconv2 MFMA (IC=64 IH=IW=8 OC=32) -> sInD3h f16 padded layout
  {
    const int px = w * 16 + n;
    const int Y = px >> 3, X = px & 7;
    const int ibase = ((Y + 1) * 10 + (X + 1)) * 72 + q * 8;
    float b4[2][4];
#pragma unroll
    for (int mi = 0; mi < 2; mi++)
#pragma unroll
      for (int r = 0; r < 4; r++) b4[mi][r] = db2[mi * 16 + q * 4 + r];
#pragma unroll
    for (int c = 0; c < 4; c++) {
      const int cy = c >> 1, cx = c & 1;
      floatx4 acc[2];
      acc[0] = (floatx4){0.f, 0.f, 0.f, 0.f};
      acc[1] = (floatx4){0.f, 0.f, 0.f, 0.f};
      for (int ks = 0; ks < 2; ks++) {
        uint4 af[2][4];
#pragma unroll
        for (int mi = 0; mi < 2; mi++)
#pragma unroll
          for (int tt = 0; tt < 4; tt++) {
            const int t2 = tt >> 1, t3 = tt & 1;
            const int ky = ((cy + 1) & 1) + 2 * t2, kx = ((cx + 1) & 1) + 2 * t3;
            af[mi][tt] = *reinterpret_cast<const uint4*>(
                wd2 + (size_t)((ky * 4 + kx) * 32 + mi * 16 + n) * 64 + ks * 32 + q * 8);
          }
#pragma unroll
        for (int tt = 0; tt < 4; tt++) {
          const int t2 = tt >> 1, t3 = tt & 1;
          const int toff = ((cy - t2) * 10 + (cx - t3)) * 72 + ks * 32;
          uint4 bf = *reinterpret_cast<const uint4*>(&sInD2[ibase + toff]);
#pragma unroll
          for (int mi = 0; mi < 2; mi++)
            acc[mi] = __builtin_amdgcn_mfma_f32_16x16x32_bf16(u2s(af[mi][tt]), u2s(bf),
                                                              acc[mi], 0, 0, 0);
        }
      }
      const int oy = 2 * Y + cy, ox = 2 * X + cx;
#pragma unroll
      for (int mi = 0; mi < 2; mi++) {
        const unsigned int lo =
            (unsigned int)f2h(fmaxf(acc[mi][0] + b4[mi][0], 0.f)) |
            ((unsigned int)f2h(fmaxf(acc[mi][1] + b4[mi][1], 0.f)) << 16);
        const unsigned int hi =
            (unsigned int)f2h(fmaxf(acc[mi][2] + b4[mi][2], 0.f)) |
            ((unsigned int)f2h(fmaxf(acc[mi][3] + b4[mi][3], 0.f)) << 16);
        *reinterpret_cast<uint2*>(&sInD3h[oy * D3_ROW + ox * D3_PX + mi * 16 + q * 4]) =
            make_uint2(lo, hi);
      }
    }
  }
  __syncthreads();
  // ---- deconv3 (f16 dot2 over ic, OC=1, sigmoid, REMAP) from sInD3h
  {
    const int oy = tid >> 3;               // 0..31
    const int rem2 = tid & 7;
    const int cpar = rem2 >> 2, qq = rem2 & 3;
    const int py = (oy + 1) & 1, pc = (cpar + 1) & 1;
    const int ixb0 = (cpar + 1 - pc) >> 1;
    const int xlo = ixb0 - 1 + qq * 4;
    float acc[4] = {0.f, 0.f, 0.f, 0.f};
    const float bv = b3[0];
#pragma unroll
    for (int u2 = 0; u2 < 2; u2++) {
      const int ky = py + 2 * u2;
      const int iy = (oy + 1 - ky) >> 1;
      if (iy < 0 || iy >= 16) continue;
      const _Float16* rowp = &sInD3h[iy * D3_ROW];
      const uint2* wAp = reinterpret_cast<const uint2*>(&sW3h[(ky * 4 + pc) * 32]);
      const uint2* wBp = reinterpret_cast<const uint2*>(&sW3h[(ky * 4 + pc + 2) * 32]);
#pragma unroll
      for (int kb = 0; kb < 8; kb++) {
        uint2 xv[5];
#pragma unroll
        for (int x = 0; x < 5; x++) {
          const int ix = xlo + x;
          xv[x] = (ix >= 0 && ix < 16)
              ? *reinterpret_cast<const uint2*>(&rowp[ix * D3_PX + kb * 4])
              : make_uint2(0u, 0u);
        }
        const uint2 wa = wAp[kb], wb = wBp[kb];
#pragma unroll
        for (int j = 0; j < 4; j++) {
          acc[j] = fdot2w(u2h(wa.x), u2h(xv[j + 1].x), acc[j]);
          acc[j] = fdot2w(u2h(wa.y), u2h(xv[j + 1].y), acc[j]);
          acc[j] = fdot2w(u2h(wb.x), u2h(xv[j].x), acc[j]);
          acc[j] = fdot2w(u2h(wb.y), u2h(xv[j].y), acc[j]);
        }
      }
    }
    const int fo = b * 64 + t;  // REMAP (t*32+b -> b*64+t)
    float* yf = out + (size_t)fo * 1024;
#pragma unroll
    for (int j = 0; j < 4; j++)
      yf[oy * 32 + (cpar + 2 * (qq * 4 + j))] = rcpf(1.f + __expf(-(acc[j] + bv)));
  }
}

// ==================== launch ====================
extern "C" void kernel_launch(void* const* d_in, const int* in_sizes, int n_in,
                              void* d_out, int out_size, void* d_ws, size_t ws_size,
                              hipStream_t stream) {
  const float* obs = (const float*)d_in[0];
  const float* actions = (const float*)d_in[1];
  const float* noise = (const float*)d_in[2];
  const float* enc_w1 = (const float*)d_in[3];
  const float* enc_b1 = (const float*)d_in[4];
  const float* enc_w2 = (const float*)d_in[5];
  const float* enc_b2 = (const float*)d_in[6];
  const float* enc_w3 = (const float*)d_in[7];
  const float* enc_b3 = (const float*)d_in[8];
  const float* enc_pw = (const float*)d_in[9];
  const float* enc_pb = (const float*)d_in[10];
  const float* dec_pw = (const float*)d_in[11];
  const float* dec_pb = (const float*)d_in[12];
  const float* dec_w1 = (const float*)d_in[13];
  const float* dec_b1 = (const float*)d_in[14];
  const float* dec_w2 = (const float*)d_in[15];
  const float* dec_b2 = (const float*)d_in[16];
  const float* dec_w3 = (const float*)d_in[17];
  const float* dec_b3 = (const float*)d_in[18];
  const float* gru_wih = (const float*)d_in[19];
  const float* gru_whh = (const float*)d_in[20];
  const float* gru_bih = (const float*)d_in[21];
  const float* gru_bhh = (const float*)d_in[22];
  const float* pri_w1 = (const float*)d_in[23];
  const float* pri_b1 = (const float*)d_in[24];
  const float* pri_w2 = (const float*)d_in[25];
  const float* pri_b2 = (const float*)d_in[26];
  const float* pri_w3 = (const float*)d_in[27];
  const float* pri_b3 = (const float*)d_in[28];
  const float* pos_w1 = (const float*)d_in[29];
  const float* pos_b1 = (const float*)d_in[30];
  const float* pos_w2 = (const float*)d_in[31];
  const float* pos_b2 = (const float*)d_in[32];
  const float* pos_w3 = (const float*)d_in[33];
  const float* pos_b3 = (const float*)d_in[34];

  float* out = (float*)d_out;
  float* ws = (float*)d_ws;
  float* HS = ws + WS_HS;
  float* POSL1E = ws + WS_POSL1E;
  float* GIA = ws + WS_GIA;
  unsigned short* WP1H = (unsigned short*)(ws + WS_WP1H);
  unsigned short* WP2 = (unsigned short*)(ws + WS_WP2);
  unsigned short* WP3 = (unsigned short*)(ws + WS_WP3);
  unsigned short* WWHH = (unsigned short*)(ws + WS_WWHH);
  unsigned short* WIHZ = (unsigned short*)(ws + WS_WIHZ);
  unsigned short* WC2 = (unsigned short*)(ws + WS_WC2);
  unsigned short* WC3 = (unsigned short*)(ws + WS_WC3);
  unsigned short* WD1 = (unsigned short*)(ws + WS_WD1);
  unsigned short* WD2 = (unsigned short*)(ws + WS_WD2);
  unsigned short* DLIN = (unsigned short*)(ws + WS_DLIN);
  unsigned short* DECWF = (unsigned short*)(ws + WS_DECWF);
  unsigned short* QW1F = (unsigned short*)(ws + WS_QW1F);
  unsigned short* QW2F = (unsigned short*)(ws + WS_QW2F);
  unsigned short* QW3F = (unsigned short*)(ws + WS_QW3F);

  // unified prep
  PPAll pp;
  pp.m[0]  = {enc_pw, ws + WS_ENCT, 64 * 1024, 10, 64, 1024};
  pp.m[1]  = {dec_pw, DECWF, 1024 * 160, 0, 0, 0};
  pp.m[2]  = {pri_w1, QW1F, 128 * 160, 6, 0, 0};
  pp.m[3]  = {pri_w2, QW2F, 128 * 128, 0, 0, 0};
  pp.m[4]  = {pri_w3, QW3F, 64 * 128, 0, 0, 0};
  pp.m[5]  = {pos_w1, ws + WS_PW1T, 128 * 192, 10, 128, 192};
  pp.m[6]  = {gru_wih, ws + WS_WIHT, 384 * 34, 10, 384, 34};
  pp.m[7]  = {pos_w1, WP1H, 128 * 128, 1, 0, 0};
  pp.m[8]  = {pos_w2, WP2, 128 * 128, 0, 0, 0};
  pp.m[9]  = {pos_w3, WP3, 64 * 128, 0, 0, 0};
  pp.m[10] = {gru_whh, WWHH, 384 * 128, 0, 0, 0};
  pp.m[11] = {gru_wih, WIHZ, 384 * 32, 2, 0, 0};
  pp.m[12] = {enc_w2, WC2, 16 * 64 * 32, 3, 64, 32};
  pp.m[13] = {enc_w3, WC3, 16 * 64 * 64, 3, 64, 64};
  pp.m[14] = {dec_w1, WD1, 16 * 64 * 64, 4, 64, 64};
  pp.m[15] = {dec_w2, WD2, 16 * 32 * 64, 4, 32, 64};
  hipLaunchKernelGGL(k_prep, dim3(32, 16), dim3(256), 0, stream, pp);

  // fused encoder (conv1..pre)
  k_enc<<<NF, 256, 0, stream>>>(obs, actions, enc_w1, enc_b1, WC2, enc_b2,
                                WC3, enc_b3, ws + WS_ENCT, enc_pb,
                                ws + WS_PW1T, pos_b1, ws + WS_WIHT, gru_bih,
                                gru_bhh, POSL1E, GIA);

  // sequential core
  k_rssm4<<<NB, 512, 0, stream>>>(POSL1E, GIA, noise, WP1H, WP2, WP3, WWHH, WIHZ,
                                  pos_b2, pos_b3, HS, out);

  // declin GEMM + prior GEMM chain (single dispatch)
  k_post<<<2176, 256, 0, stream>>>(HS, out + OUT_ZS, DECWF, dec_pb, DLIN,
                                   actions, QW1F, pri_b1, QW2F, pri_b2,
                                   QW3F, pri_b3, out);

  // fused decoder (deconv1..deconv3)
  k_dec<<<NF, 256, 0, stream>>>(DLIN, WD1, dec_b1, WD2, dec_b2, dec_w3, dec_b3, out);
}

// Round 10
// 433.370 us; speedup vs baseline: 1.0103x; 1.0103x over previous
//
#include <hip/hip_runtime.h>
#include <math.h>

// ---------------- problem dims ----------------
#define NB 32
#define NT 64
#define NF 2048  // NB*NT frames

// ---------------- output float offsets ----------------
#define OUT_ZS    2097152
#define OUT_PRM   (OUT_ZS + 65536)
#define OUT_PRLS  (OUT_PRM + 65536)
#define OUT_PM    (OUT_PRLS + 65536)
#define OUT_PLS   (OUT_PM + 65536)
#define OUT_HF    (OUT_PLS + 65536)

// ---------------- workspace float offsets ----------------
#define WS_HS    27394048   // 64*32*128
#define WS_ENCWF 27656192   // enc_pw f16 [64][1024]
#define WS_WP1H  27885568   // 128x128 f16
#define WS_WP2   27893760   // 128x128 f16
#define WS_WP3   27901952   // 64x128 f16
#define WS_WWHH  27906048   // 384x128 f16
#define WS_WIHZ  27930624   // 384x32 f16
#define WS_PW1E  27977984   // pos_w1 e-part f16 [128][64]
#define WS_WIHT  28002560   // 34x384
#define WS_WC2   16777216   // 16*64*32 bf16
#define WS_WC3   (WS_WC2 + 16384)
#define WS_WD1   (WS_WC3 + 32768)
#define WS_WD2   (WS_WD1 + 32768)
#define WS_DLIN  16908288   // 2048x1024 bf16 (declin output)
#define WS_DECWF 17960960   // 1024x160 f16 (dec_pw rows)
#define WS_QW1F  18045952   // 128x160 f16 (pri_w1 padded 130->160)
#define WS_QW2F  18057216   // 128x128 f16
#define WS_QW3F  18066432   // 64x128 f16
#define WS_XE    18874368   // 2048x1024 f16 (conv stack output)
#define WS_POSL1E 25165824  // 2048*128
#define WS_GIA    (WS_POSL1E + 262144)  // 2048*384

// ==================== helpers ====================
typedef __attribute__((ext_vector_type(8))) short short8;
typedef __attribute__((ext_vector_type(4))) float floatx4;
typedef _Float16 __attribute__((ext_vector_type(2))) half2v;
typedef _Float16 __attribute__((ext_vector_type(8))) half8;
union U4S8 { uint4 u; short8 s; };
__device__ __forceinline__ short8 u2s(uint4 u) { U4S8 x; x.u = u; return x.s; }
union U4HH { uint4 u; half8 h; };
__device__ __forceinline__ half8 u2hh(uint4 u) { U4HH x; x.u = u; return x.h; }

__device__ __forceinline__ float rcpf(float x) {
#if __has_builtin(__builtin_amdgcn_rcpf)
  return __builtin_amdgcn_rcpf(x);
#else
  return 1.f / x;
#endif
}
__device__ __forceinline__ float eluf(float a) {
  return (a > 0.f) ? a : (__expf(a) - 1.f);
}
__device__ __forceinline__ float sigm(float a) {
  return rcpf(1.f + __expf(-a));
}
__device__ __forceinline__ float tanhfast(float x) {
  const float e = __expf(fminf(-2.f * x, 60.f));
  return (1.f - e) * rcpf(1.f + e);
}
__device__ __forceinline__ unsigned short f2bf(float f) {
  unsigned int u = __float_as_uint(f);
  u += 0x7fffu + ((u >> 16) & 1u);
  return (unsigned short)(u >> 16);
}
__device__ __forceinline__ unsigned short f2h(float f) {
  _Float16 h = (_Float16)f;
  return __builtin_bit_cast(unsigned short, h);
}
__device__ __forceinline__ unsigned int pack2h(float a, float b) {
  return (unsigned int)f2h(a) | ((unsigned int)f2h(b) << 16);
}
union UH2 { unsigned int u; half2v h; };
__device__ __forceinline__ half2v u2h(unsigned int u) { UH2 x; x.u = u; return x.h; }

__device__ __forceinline__ float fdot2w(half2v a, half2v b, float c) {
#if __has_builtin(__builtin_amdgcn_fdot2)
  return __builtin_amdgcn_fdot2(a, b, c, false);
#else
  return fmaf((float)a[0], (float)b[0], fmaf((float)a[1], (float)b[1], c));
#endif
}

// f16-pair dot: 8 MACs via 4 v_dot2_f32_f16 into 4 independent accumulators.
union U4H2 { uint4 u; half2v h[4]; };
__device__ __forceinline__ void dot8h(uint4 w, uint4 x,
                                      float& a0, float& a1, float& a2, float& a3) {
  U4H2 W; W.u = w;
  U4H2 X; X.u = x;
  a0 = fdot2w(W.h[0], X.h[0], a0);
  a1 = fdot2w(W.h[1], X.h[1], a1);
  a2 = fdot2w(W.h[2], X.h[2], a2);
  a3 = fdot2w(W.h[3], X.h[3], a3);
}

// ==================== unified prep: fp32 transposes + f16/bf16 packs =======
// mode 10: fp32 transpose dst[c*A+r]=src[r*B+c]
// mode 0: f16 direct; 1: pos_w1 h-part (f16); 2: wih z-part (f16);
// mode 3: conv w [oc][ic][t]->[t][oc][ic] (bf16); 4: deconv w (bf16)
// mode 6: pri_w1 pad K 130->160 (f16); 7: pos_w1 e-part [128][64] (f16)
struct PP { const float* src; void* dst; int n; int mode; int A; int B; };
struct PPAll { PP m[16]; };

__global__ __launch_bounds__(256) void k_prep(PPAll a) {
  PP p = a.m[blockIdx.y];
  for (int i = blockIdx.x * 256 + threadIdx.x; i < p.n; i += gridDim.x * 256) {
    if (p.mode == 10) {
      const int r = i / p.B, c = i - r * p.B;
      ((float*)p.dst)[c * p.A + r] = p.src[i];
    } else {
      float v;
      if (p.mode == 0) v = p.src[i];
      else if (p.mode == 1) v = p.src[(i >> 7) * 192 + (i & 127)];
      else if (p.mode == 2) v = p.src[(i >> 5) * 34 + (i & 31)];
      else if (p.mode == 6) {
        const int o = i / 160, k = i - o * 160;
        v = (k < 130) ? p.src[o * 130 + k] : 0.f;
      } else if (p.mode == 7) {
        v = p.src[(i >> 6) * 192 + 128 + (i & 63)];
      } else {
        const int ab = p.A * p.B;
        const int t = i / ab, rem = i - t * ab;
        const int oc = rem / p.B, ic = rem - oc * p.B;
        v = (p.mode == 3) ? p.src[(oc * p.B + ic) * 16 + t]
                          : p.src[(ic * p.A + oc) * 16 + t];
      }
      ((unsigned short*)p.dst)[i] = (p.mode <= 2 || p.mode >= 6) ? f2h(v) : f2bf(v);
    }
  }
}

// ==================== fused encoder: conv1->conv2->conv3 -> XE f16 =========
// one block per frame f = b*64+t ; enclin/pre moved to k_emb (batched GEMM).
__global__ __launch_bounds__(256, 3) void k_enc(
    const float* __restrict__ obs, const float* __restrict__ act,
    const float* __restrict__ w1, const float* __restrict__ b1,
    const unsigned short* __restrict__ wc2, const float* __restrict__ b2,
    const unsigned short* __restrict__ wc3, const float* __restrict__ b3,
    const float* __restrict__ wihT, const float* __restrict__ bih,
    const float* __restrict__ bhh,
    unsigned short* __restrict__ xe, float* __restrict__ gia) {
  const int f = blockIdx.x, tid = threadIdx.x;
  const int w = tid >> 6, l = tid & 63, q = l >> 4, n = l & 15;
  __shared__ float sIn1[32 * 33];
  __shared__ float sW1[512];
  __shared__ float sB1[32];
  __shared__ __align__(16) unsigned short sIn2[18 * 18 * 40];  // conv2 haloed in
  __shared__ __align__(16) unsigned short sIn3[10 * 10 * 72];  // conv3 haloed in
  __shared__ __align__(16) _Float16 sXeh[1024];                // conv3 out f16
  __shared__ float sA2[2];

  // ---- stage conv1 inputs + zero haloed buffers
  {
    const float* in = obs + (size_t)f * 1024;
    for (int i = tid; i < 1024; i += 256) sIn1[(i >> 5) * 33 + (i & 31)] = in[i];
    for (int i = tid; i < 512; i += 256) sW1[i] = w1[i];
    if (tid < 32) sB1[tid] = b1[tid];
    if (tid < 2) sA2[tid] = act[(size_t)f * 2 + tid];
    unsigned int* z2 = (unsigned int*)sIn2;
    for (int i = tid; i < 18 * 18 * 40 / 2; i += 256) z2[i] = 0u;
    unsigned int* z3 = (unsigned int*)sIn3;
    for (int i = tid; i < 10 * 10 * 72 / 2; i += 256) z3[i] = 0u;
  }
  __syncthreads();
  // ---- conv1 (fp32) -> sIn2 interior
  for (int r = tid; r < 512; r += 256) {       // r = oc*16 + oy
    const int oc = r >> 4, oy = r & 15;
    float acc[16];
    const float bv = sB1[oc];
#pragma unroll
    for (int j = 0; j < 16; j++) acc[j] = bv;
#pragma unroll
    for (int ky = 0; ky < 4; ky++) {
      const int iy = 2 * oy + ky - 1;
      if (iy < 0 || iy >= 32) continue;
#pragma unroll
      for (int kx = 0; kx < 4; kx++) {
        const float wv = sW1[oc * 16 + ky * 4 + kx];
#pragma unroll
        for (int j = 0; j < 16; j++) {
          const int ix = 2 * j + kx - 1;
          if (ix >= 0 && ix < 32) acc[j] += wv * sIn1[iy * 33 + ix];
        }
      }
    }
#pragma unroll
    for (int j = 0; j < 16; j++)
      sIn2[((oy + 1) * 18 + (j + 1)) * 40 + oc] = f2bf(fmaxf(acc[j], 0.f));
  }
  __syncthreads();
  // ---- conv2 MFMA (IC=32 OC=64, 16x16 out) -> sIn3 interior
  {
    int base[4];
#pragma unroll
    for (int nt = 0; nt < 4; nt++) {
      const int px = nt * 16 + n, oy = px >> 3, ox = px & 7;
      base[nt] = ((2 * oy + 1) * 18 + (2 * ox + 1)) * 40 + q * 8;
    }
    floatx4 acc[4];
#pragma unroll
    for (int nt = 0; nt < 4; nt++) acc[nt] = (floatx4){0.f, 0.f, 0.f, 0.f};
    uint4 af[16];
#pragma unroll
    for (int t = 0; t < 16; t++)
      af[t] = *reinterpret_cast<const uint4*>(wc2 + (size_t)(t * 64 + w * 16 + n) * 32 + q * 8);
#pragma unroll
    for (int t = 0; t < 16; t++) {
      const int toff = ((t / 4 - 1) * 18 + (t % 4 - 1)) * 40;
#pragma unroll
      for (int nt = 0; nt < 4; nt++) {
        uint4 bf = *reinterpret_cast<const uint4*>(&sIn2[base[nt] + toff]);
        acc[nt] = __builtin_amdgcn_mfma_f32_16x16x32_bf16(u2s(af[t]), u2s(bf), acc[nt], 0, 0, 0);
      }
    }
    float b4[4];
#pragma unroll
    for (int r = 0; r < 4; r++) b4[r] = b2[w * 16 + q * 4 + r];
    __syncthreads();
#pragma unroll
    for (int nt = 0; nt < 4; nt++) {
      const int px = nt * 16 + n, oy = px >> 3, ox = px & 7;
#pragma unroll
      for (int r = 0; r < 4; r++)
        sIn3[((oy + 1) * 10 + (ox + 1)) * 72 + (w * 16 + q * 4 + r)] =
            f2bf(fmaxf(acc[nt][r] + b4[r], 0.f));
    }
  }
  __syncthreads();
  // ---- conv3 MFMA (IC=64 OC=64, 4x4 out) -> sXeh f16 [ch*16+px]
  {
    const int oy = n >> 2, ox = n & 3;
    const int ibase = ((2 * oy + 1) * 10 + (2 * ox + 1)) * 72 + q * 8;
    floatx4 acc = (floatx4){0.f, 0.f, 0.f, 0.f};
    for (int ks = 0; ks < 2; ks++) {
      uint4 af[16];
#pragma unroll
      for (int t = 0; t < 16; t++)
        af[t] = *reinterpret_cast<const uint4*>(
            wc3 + (size_t)(t * 64 + w * 16 + n) * 64 + ks * 32 + q * 8);
#pragma unroll
      for (int t = 0; t < 16; t++) {
        const int toff = ((t / 4 - 1) * 10 + (t % 4 - 1)) * 72 + ks * 32;
        uint4 bf = *reinterpret_cast<const uint4*>(&sIn3[ibase + toff]);
        acc = __builtin_amdgcn_mfma_f32_16x16x32_bf16(u2s(af[t]), u2s(bf), acc, 0, 0, 0);
      }
    }
#pragma unroll
    for (int r = 0; r < 4; r++) {
      const int ch = w * 16 + q * 4 + r;
      sXeh[ch * 16 + n] = (_Float16)fmaxf(acc[r] + b3[ch], 0.f);
    }
  }
  __syncthreads();
  // ---- write XE (coalesced uint2) + gia (a-part, interleaved, + bhh)
  *reinterpret_cast<uint2*>(&xe[(size_t)f * 1024 + tid * 4]) =
      *reinterpret_cast<const uint2*>(&sXeh[tid * 4]);
  if (tid >= 128) {
#pragma unroll
    for (int jj = 0; jj < 3; jj++) {
      const int j = (tid - 128) + jj * 128;
      gia[(size_t)f * 384 + (tid - 128) * 3 + jj] =
          bih[j] + bhh[j] + wihT[32 * 384 + j] * sA2[0] + wihT[33 * 384 + j] * sA2[1];
    }
  }
}

// ==================== embed + pos-L1 batched GEMM ==========================
// 128 blocks x 16 frames: E = XE(2048x1024)@enc_pw^T + encb;
// posl1e = E @ pw1e^T + pb1 (fp32 out). Same MFMA template as k_post.
__global__ __launch_bounds__(256) void k_emb(
    const unsigned short* __restrict__ xe,
    const unsigned short* __restrict__ encwf, const float* __restrict__ encb,
    const unsigned short* __restrict__ pw1e, const float* __restrict__ pb1,
    float* __restrict__ posl1e) {
  const int tid = threadIdx.x;
  const int fBase = blockIdx.x * 16;
  const int w = tid >> 6, l = tid & 63, q = l >> 4, n = l & 15;
  __shared__ __align__(16) _Float16 sB[16][1032];
  __shared__ __align__(16) _Float16 sE2[16][72];
  // stage 16 frames x 1024 f16 = 2048 uint4; 128 uint4 per frame
#pragma unroll
  for (int j = 0; j < 8; j++) {
    const int i4 = tid + j * 256;
    const int fr = i4 >> 7, kq = (i4 & 127) * 8;
    *reinterpret_cast<uint4*>(&sB[fr][kq]) =
        *reinterpret_cast<const uint4*>(&xe[(size_t)(fBase + fr) * 1024 + kq]);
  }
  __syncthreads();
  // ---- GEMM1: E[16f x 64o], K=1024
  {
    const int oB = w * 16;
    floatx4 acc = (floatx4){0.f, 0.f, 0.f, 0.f};
#pragma unroll
    for (int ks = 0; ks < 32; ks++) {
      uint4 a = *reinterpret_cast<const uint4*>(
          &encwf[(size_t)(oB + n) * 1024 + ks * 32 + q * 8]);
      uint4 bb = *reinterpret_cast<const uint4*>(&sB[n][ks * 32 + q * 8]);
      acc = __builtin_amdgcn_mfma_f32_16x16x32_f16(u2hh(a), u2hh(bb), acc, 0, 0, 0);
    }
    const int o0 = oB + q * 4;
    *reinterpret_cast<unsigned int*>(&sE2[n][o0]) =
        pack2h(acc[0] + encb[o0], acc[1] + encb[o0 + 1]);
    *reinterpret_cast<unsigned int*>(&sE2[n][o0 + 2]) =
        pack2h(acc[2] + encb[o0 + 2], acc[3] + encb[o0 + 3]);
  }
  __syncthreads();
  // ---- GEMM2: posl1e[16f x 128o], K=64
#pragma unroll
  for (int g = 0; g < 2; g++) {
    const int oB = g * 64 + w * 16;
    floatx4 acc = (floatx4){0.f, 0.f, 0.f, 0.f};
#pragma unroll
    for (int ks = 0; ks < 2; ks++) {
      uint4 a = *reinterpret_cast<const uint4*>(&pw1e[(oB + n) * 64 + ks * 32 + q * 8]);
      uint4 bb = *reinterpret_cast<const uint4*>(&sE2[n][ks * 32 + q * 8]);
      acc = __builtin_amdgcn_mfma_f32_16x16x32_f16(u2hh(a), u2hh(bb), acc, 0, 0, 0);
    }
    const int o0 = oB + q * 4;
#pragma unroll
    for (int r = 0; r < 4; r++)
      posl1e[(size_t)(fBase + n) * 128 + o0 + r] = acc[r] + pb1[o0 + r];
  }
}

// ==================== recurrent core (f16 dot2 + shfl reductions) ==========
// 32 blocks x 512 threads. Per step, 4 barriers (round-6 verified structure).
__global__ __launch_bounds__(512, 2) void k_rssm4(
    const float* __restrict__ posl1e, const float* __restrict__ gia,
    const float* __restrict__ noise,
    const unsigned short* __restrict__ wp1h, const unsigned short* __restrict__ wp2,
    const unsigned short* __restrict__ wp3, const unsigned short* __restrict__ wwhh,
    const unsigned short* __restrict__ wihz,
    const float* __restrict__ pb2, const float* __restrict__ pb3,
    float* __restrict__ hs, float* __restrict__ out) {
  const int b = blockIdx.x, tid = threadIdx.x;
  const int R = tid >> 2, ks4 = tid & 3;
  __shared__ __align__(16) _Float16 sHh[128];
  __shared__ __align__(16) _Float16 sL1h[128];
  __shared__ __align__(16) _Float16 sL2h[128];
  __shared__ __align__(16) _Float16 sZh[32];
  __shared__ float sGh[384];   // interleaved: [R*3 + gate]

  uint4 wA4[4][4];  // j=0: L1 row R; j=1..3: whh rows R,R+128,R+256; K-quarter ks4
  {
#pragma unroll
    for (int j = 0; j < 4; j++) {
      const unsigned short* p = (j == 0)
          ? (wp1h + R * 128)
          : (wwhh + (size_t)((j - 1) * 128 + R) * 128);
      const uint4* pv = reinterpret_cast<const uint4*>(p + ks4 * 32);
#pragma unroll
      for (int i = 0; i < 4; i++) wA4[j][i] = pv[i];
    }
  }
  uint4 wB[4];
  {
    const unsigned short* rowB = wp2 + R * 128 + ks4 * 32;
#pragma unroll
    for (int i = 0; i < 4; i++) wB[i] = reinterpret_cast<const uint4*>(rowB)[i];
  }
  uint4 wC[2];
  {
    // row-paired output mapping: r = tid>>3, o = (r>>1) + 32*(r&1)
    const int r = tid >> 3;
    const int o = (r >> 1) + ((r & 1) << 5);
    const unsigned short* rowC = wp3 + o * 128 + (tid & 7) * 16;
#pragma unroll
    for (int i = 0; i < 2; i++) wC[i] = reinterpret_cast<const uint4*>(rowC)[i];
  }
  uint4 wD[3][4];
  if (tid < 128) {
#pragma unroll
    for (int j = 0; j < 3; j++) {
      const unsigned short* rowD = wihz + (size_t)(tid + 128 * j) * 32;
#pragma unroll
      for (int i = 0; i < 4; i++) wD[j][i] = reinterpret_cast<const uint4*>(rowD)[i];
    }
  }
  const bool zlane = (tid & 15) == 0;   // j = tid>>4
  const int jz = tid >> 4;
  const float pb2R = pb2[R];
  const float pb3mR = zlane ? pb3[jz] : 0.f;
  const float pb3sR = zlane ? pb3[jz + 32] : 0.f;

  float h_reg = 0.f;
  float pl1R = 0.f, epsR = 0.f;
  float3 gaR = {0.f, 0.f, 0.f};
  if (ks4 == 0) pl1R = posl1e[(size_t)(b * 64) * 128 + R];
  if (tid < 128) {
    gaR = *reinterpret_cast<const float3*>(&gia[(size_t)(b * 64) * 384 + tid * 3]);
    sHh[tid] = (_Float16)0.f;
    hs[(size_t)b * 128 + tid] = 0.f;
  }
  if (zlane) epsR = noise[(size_t)b * 32 + jz];
  __syncthreads();

  for (int t = 0; t < 64; ++t) {
    const int tn = (t < 63) ? t + 1 : 63;
    float pl1N = 0.f, epsN = 0.f;
    float3 gaN = {0.f, 0.f, 0.f};
    if (ks4 == 0) pl1N = posl1e[(size_t)(b * 64 + tn) * 128 + R];
    if (tid < 128)
      gaN = *reinterpret_cast<const float3*>(&gia[(size_t)(b * 64 + tn) * 384 + tid * 3]);
    if (zlane) epsN = noise[(size_t)(tn * 32 + b) * 32 + jz];

    // ---- A: L1 + gh (K-quarter per thread, 4 rows)
    {
      const uint4* xs = reinterpret_cast<const uint4*>(sHh) + ks4 * 4;
      const uint4 x0 = xs[0], x1 = xs[1], x2 = xs[2], x3 = xs[3];
      float part[4];
#pragma unroll
      for (int j = 0; j < 4; j++) {
        float p0 = 0.f, p1 = 0.f, p2 = 0.f, p3 = 0.f;
        dot8h(wA4[j][0], x0, p0, p1, p2, p3);
        dot8h(wA4[j][1], x1, p0, p1, p2, p3);
        dot8h(wA4[j][2], x2, p0, p1, p2, p3);
        dot8h(wA4[j][3], x3, p0, p1, p2, p3);
        part[j] = (p0 + p1) + (p2 + p3);
      }
#pragma unroll
      for (int j = 0; j < 4; j++) {
        part[j] += __shfl_xor(part[j], 1);
        part[j] += __shfl_xor(part[j], 2);
      }
      if (ks4 == 0) {
        sL1h[R] = (_Float16)eluf(part[0] + pl1R);
        sGh[R * 3] = part[1];
        sGh[R * 3 + 1] = part[2];
        sGh[R * 3 + 2] = part[3];
      }
    }
    __syncthreads();
    // ---- B: L2 (4-way K-split, in-wave combine)
    {
      float a0 = 0.f, a1 = 0.f, a2 = 0.f, a3 = 0.f;
      const uint4* xs = reinterpret_cast<const uint4*>(sL1h) + ks4 * 4;
#pragma unroll
      for (int i = 0; i < 4; i++) dot8h(wB[i], xs[i], a0, a1, a2, a3);
      float p = (a0 + a1) + (a2 + a3);
      p += __shfl_xor(p, 1);
      p += __shfl_xor(p, 2);
      if (ks4 == 0) sL2h[R] = (_Float16)eluf(p + pb2R);
    }
    __syncthreads();
    // ---- C: L3 (8-way K-split) + in-wave pm/pls pairing + z
    {
      float a0 = 0.f, a1 = 0.f, a2 = 0.f, a3 = 0.f;
      const uint4* xs = reinterpret_cast<const uint4*>(sL2h) + (tid & 7) * 2;
      dot8h(wC[0], xs[0], a0, a1, a2, a3);
      dot8h(wC[1], xs[1], a0, a1, a2, a3);
      float p = (a0 + a1) + (a2 + a3);
      p += __shfl_xor(p, 1);
      p += __shfl_xor(p, 2);
      p += __shfl_xor(p, 4);            // all 8 lanes of row hold total
      const float pq = __shfl_xor(p, 8); // partner row's total (pls row)
      if (zlane) {
        const float pm = p + pb3mR;
        float pls = pq + pb3sR;
        pls = fminf(fmaxf(pls, -5.f), 2.f);
        const float z = pm + __expf(pls) * epsR;
        sZh[jz] = (_Float16)z;
        const int o = (b * 64 + t) * 32 + jz;
        out[OUT_ZS + o] = z;
        out[OUT_PM + o] = pm;
        out[OUT_PLS + o] = pls;
      }
    }
    __syncthreads();
    // ---- FG: gi dots (K=32) + GRU, fused on tid<128
    if (tid < 128) {
      float r0 = 0.f, r1 = 0.f, r2 = 0.f, r3 = 0.f;
      float u0 = 0.f, u1 = 0.f, u2 = 0.f, u3 = 0.f;
      float m0 = 0.f, m1 = 0.f, m2 = 0.f, m3 = 0.f;
      const uint4* xs = reinterpret_cast<const uint4*>(sZh);
#pragma unroll
      for (int i = 0; i < 4; i++) {
        const uint4 xv = xs[i];
        dot8h(wD[0][i], xv, r0, r1, r2, r3);
        dot8h(wD[1][i], xv, u0, u1, u2, u3);
        dot8h(wD[2][i], xv, m0, m1, m2, m3);
      }
      const float gr = gaR.x + ((r0 + r1) + (r2 + r3));
      const float gu = gaR.y + ((u0 + u1) + (u2 + u3));
      const float gn = gaR.z + ((m0 + m1) + (m2 + m3));
      const float ghr = sGh[tid * 3];
      const float ghu = sGh[tid * 3 + 1];
      const float ghn = sGh[tid * 3 + 2];
      const float r = sigm(gr + ghr);
      const float u = sigm(gu + ghu);
      const float n = tanhfast(gn + r * ghn);
      const float hn = (1.f - u) * n + u * h_reg;
      h_reg = hn;
      sHh[tid] = (_Float16)hn;
      if (t < 63) hs[(size_t)((t + 1) * 32 + b) * 128 + tid] = hn;
    }
    pl1R = pl1N;
    gaR = gaN;
    epsR = epsN;
    __syncthreads();
  }
  if (tid < 128) out[OUT_HF + b * 128 + tid] = h_reg;
}

// ==================== post: declin GEMM + prior GEMM chain (one dispatch) ==
// blocks [0,2048): declin (2048x160)@(160x1024) -> DLIN bf16
// blocks [2048,2176): prior 3-layer GEMM chain, 16 frames/block
__global__ __launch_bounds__(256) void k_post(
    const float* __restrict__ hs, const float* __restrict__ zs,
    const unsigned short* __restrict__ decwf, const float* __restrict__ decb,
    unsigned short* __restrict__ dlin,
    const float* __restrict__ act,
    const unsigned short* __restrict__ qw1f, const float* __restrict__ qb1,
    const unsigned short* __restrict__ qw2f, const float* __restrict__ qb2,
    const unsigned short* __restrict__ qw3f, const float* __restrict__ qb3,
    float* __restrict__ out) {
  const int tid = threadIdx.x;
  const int bid = blockIdx.x;
  const int w = tid >> 6, l = tid & 63, q = l >> 4, n = l & 15;
  __shared__ __align__(16) _Float16 sB[16][168];
  __shared__ __align__(16) _Float16 sB2[16][136];

  if (bid < 2048) {
    // ---------------- declin ----------------
    const int otile = bid & 15;
    const int fBase = (bid >> 4) * 16;
    for (int i = tid; i < 2560; i += 256) {
      const int fr = i / 160, k = i - fr * 160;
      const int f = fBase + fr;                    // hs-order: f = t*32+b
      float v;
      if (k < 128) v = hs[(size_t)f * 128 + k];
      else v = zs[(size_t)((f & 31) * 64 + (f >> 5)) * 32 + (k - 128)];
      sB[fr][k] = (_Float16)v;
    }
    __syncthreads();
    const int oB = otile * 64 + w * 16;
    floatx4 acc = (floatx4){0.f, 0.f, 0.f, 0.f};
#pragma unroll
    for (int ks = 0; ks < 5; ks++) {
      uint4 a = *reinterpret_cast<const uint4*>(&decwf[(size_t)(oB + n) * 160 + ks * 32 + q * 8]);
      uint4 bb = *reinterpret_cast<const uint4*>(&sB[n][ks * 32 + q * 8]);
      acc = __builtin_amdgcn_mfma_f32_16x16x32_f16(u2hh(a), u2hh(bb), acc, 0, 0, 0);
    }
    const int o0 = oB + q * 4;
    const int f = fBase + n;
    const unsigned int lo = (unsigned int)f2bf(acc[0] + decb[o0]) |
                            ((unsigned int)f2bf(acc[1] + decb[o0 + 1]) << 16);
    const unsigned int hi = (unsigned int)f2bf(acc[2] + decb[o0 + 2]) |
                            ((unsigned int)f2bf(acc[3] + decb[o0 + 3]) << 16);
    *reinterpret_cast<uint2*>(&dlin[(size_t)f * 1024 + o0]) = make_uint2(lo, hi);
    return;
  }
  // ---------------- prior chain ----------------
  const int fBase = (bid - 2048) * 16;
  for (int i = tid; i < 2560; i += 256) {
    const int fr = i / 160, k = i - fr * 160;
    const int f = fBase + fr;
    float v = 0.f;
    if (k < 128) v = hs[(size_t)f * 128 + k];
    else if (k < 130) v = act[(size_t)((f & 31) * 64 + (f >> 5)) * 2 + (k - 128)];
    sB[fr][k] = (_Float16)v;
  }
  __syncthreads();
  // ---- layer1 (128 outs = 2 groups x 4 waves x 16), K=160
#pragma unroll
  for (int g = 0; g < 2; g++) {
    const int oB = g * 64 + w * 16;
    floatx4 acc = (floatx4){0.f, 0.f, 0.f, 0.f};
#pragma unroll
    for (int ks = 0; ks < 5; ks++) {
      uint4 a = *reinterpret_cast<const uint4*>(&qw1f[(oB + n) * 160 + ks * 32 + q * 8]);
      uint4 bb = *reinterpret_cast<const uint4*>(&sB[n][ks * 32 + q * 8]);
      acc = __builtin_amdgcn_mfma_f32_16x16x32_f16(u2hh(a), u2hh(bb), acc, 0, 0, 0);
    }
    const int o0 = oB + q * 4;
    *reinterpret_cast<unsigned int*>(&sB2[n][o0]) =
        pack2h(eluf(acc[0] + qb1[o0]), eluf(acc[1] + qb1[o0 + 1]));
    *reinterpret_cast<unsigned int*>(&sB2[n][o0 + 2]) =
        pack2h(eluf(acc[2] + qb1[o0 + 2]), eluf(acc[3] + qb1[o0 + 3]));
  }
  __syncthreads();
  // ---- layer2 (128 outs), K=128 -> writes back into sB
#pragma unroll
  for (int g = 0; g < 2; g++) {
    const int oB = g * 64 + w * 16;
    floatx4 acc = (floatx4){0.f, 0.f, 0.f, 0.f};
#pragma unroll
    for (int ks = 0; ks < 4; ks++) {
      uint4 a = *reinterpret_cast<const uint4*>(&qw2f[(oB + n) * 128 + ks * 32 + q * 8]);
      uint4 bb = *reinterpret_cast<const uint4*>(&sB2[n][ks * 32 + q * 8]);
      acc = __builtin_amdgcn_mfma_f32_16x16x32_f16(u2hh(a), u2hh(bb), acc, 0, 0, 0);
    }
    const int o0 = oB + q * 4;
    *reinterpret_cast<unsigned int*>(&sB[n][o0]) =
        pack2h(eluf(acc[0] + qb2[o0]), eluf(acc[1] + qb2[o0 + 1]));
    *reinterpret_cast<unsigned int*>(&sB[n][o0 + 2]) =
        pack2h(eluf(acc[2] + qb2[o0 + 2]), eluf(acc[3] + qb2[o0 + 3]));
  }
  __syncthreads();
  // ---- layer3 (64 outs = 4 waves x 16), K=128
  {
    const int oB = w * 16;
    floatx4 acc = (floatx4){0.f, 0.f, 0.f, 0.f};
#pragma unroll
    for (int ks = 0; ks < 4; ks++) {
      uint4 a = *reinterpret_cast<const uint4*>(&qw3f[(oB + n) * 128 + ks * 32 + q * 8]);
      uint4 bb = *reinterpret_cast<const uint4*>(&sB[n][ks * 32 + q * 8]);
      acc = __builtin_amdgcn_mfma_f32_16x16x32_f16(u2hh(a), u2hh(bb), acc, 0, 0, 0);
    }
    const int o0 = oB + q * 4;
    const int f = fBase + n;
    const int ob = ((f & 31) * 64 + (f >> 5)) * 32;
#pragma unroll
    for (int r = 0; r < 4; r++) {
      const int o = o0 + r;
      const float v = acc[r] + qb3[o];
      if (o < 32) out[OUT_PRM + ob + o] = v;
      else out[OUT_PRLS + ob + o - 32] = fminf(fmaxf(v, -5.f), 2.f);
    }
  }
}

// ==================== fused decoder: deconv1->deconv2->deconv3 =============
// one block per frame f = t*32+b ; declin input pre-computed in DLIN (bf16).
#define D3_ROW 580
#define D3_PX  36
__global__ __launch_bounds__(256, 4) void k_dec(
    const unsigned short* __restrict__ dlin,
    const unsigned short* __restrict__ wd1, const float* __restrict__ db1,
    const unsigned short* __restrict__ wd2, const float* __restrict__ db2,
    const float* __restrict__ w3, const float* __restrict__ b3,
    float* __restrict__ out) {
  const int f = blockIdx.x, tid = threadIdx.x;
  const int w = tid >> 6, l = tid & 63, q = l >> 4, n = l & 15;
  const int t = f >> 5, b = f & 31;
  __shared__ __align__(16) unsigned short sInD1[6 * 6 * 72];    // deconv1 haloed in
  __shared__ __align__(16) unsigned short sInD2[10 * 10 * 72];  // deconv2 haloed in
  __shared__ __align__(16) _Float16 sInD3h[16 * D3_ROW];        // deconv3 in, padded
  __shared__ __align__(16) _Float16 sW3h[16 * 32];              // deconv3 w [tap][ic]

  // ---- issue DLIN load early; zero halos; stage deconv3 weights
  const uint2 dv = *reinterpret_cast<const uint2*>(dlin + (size_t)f * 1024 + tid * 4);
  {
    unsigned int* z1 = (unsigned int*)sInD1;
    for (int i = tid; i < 6 * 6 * 72 / 2; i += 256) z1[i] = 0u;
    unsigned int* z2 = (unsigned int*)sInD2;
    for (int i = tid; i < 10 * 10 * 72 / 2; i += 256) z2[i] = 0u;
    for (int s = tid; s < 512; s += 256) {
      const int tap = s >> 5, icc = s & 31;
      sW3h[s] = (_Float16)w3[icc * 16 + tap];
    }
  }
  __syncthreads();
  // ---- scatter DLIN (o = tid*4..+3) into sInD1 halo interior
  {
    const int o0 = tid * 4, c = o0 >> 4, px0 = o0 & 15;
    const int Y = px0 >> 2;
    const int base = ((Y + 1) * 6 + 1) * 72 + c;
    sInD1[base] = (unsigned short)(dv.x & 0xffffu);
    sInD1[base + 72] = (unsigned short)(dv.x >> 16);
    sInD1[base + 144] = (unsigned short)(dv.y & 0xffffu);
    sInD1[base + 216] = (unsigned short)(dv.y >> 16);
  }
  __syncthreads();
  // ---- deconv1 MFMA (IC=64 IH=IW=4 OC=64) -> sInD2 interior
  {
    const int Y = n >> 2, X = n & 3;
    const int ibase = ((Y + 1) * 6 + (X + 1)) * 72 + q * 8;
    float b4[4];
#pragma unroll
    for (int r = 0; r < 4; r++) b4[r] = db1[w * 16 + q * 4 + r];
#pragma unroll
    for (int c = 0; c < 4; c++) {
      const int cy = c >> 1, cx = c & 1;
      floatx4 acc = (floatx4){0.f, 0.f, 0.f, 0.f};
      for (int ks = 0; ks < 2; ks++) {
        uint4 af[4];
#pragma unroll
        for (int tt = 0; tt < 4; tt++) {
          const int t2 = tt >> 1, t3 = tt & 1;
          const int ky = ((cy + 1) & 1) + 2 * t2, kx = ((cx + 1) & 1) + 2 * t3;
          af[tt] = *reinterpret_cast<const uint4*>(
              wd1 + (size_t)((ky * 4 + kx) * 64 + w * 16 + n) * 64 + ks * 32 + q * 8);
        }
#pragma unroll
        for (int tt = 0; tt < 4; tt++) {
          const int t2 = tt >> 1, t3 = tt & 1;
          const int toff = ((cy - t2) * 6 + (cx - t3)) * 72 + ks * 32;
          uint4 bf = *reinterpret_cast<const uint4*>(&sInD1[ibase + toff]);
          acc = __builtin_amdgcn_mfma_f32_16x16x32_bf16(u2s(af[tt]), u2s(bf), acc, 0, 0, 0);
        }
      }
      const int oy = 2 * Y + cy, ox = 2 * X + cx;
#pragma unroll
      for (int r = 0; r < 4; r++)
        sInD2[((oy + 1) * 10 + (ox + 1)) * 72 + (w * 16 + q * 4 + r)] =
            f2bf(fmaxf(acc[r] + b4[r], 0.f));
    }
  }
  __syncthreads();
  // ---- deconv2 MFMA (IC=64 IH=IW=8 OC=32) -> sInD3h f16 padded layout
  {
    const int px = w * 16 + n;
    const int Y = px >> 3, X = px & 7;
    const int ibase = ((Y + 1) * 10 + (X + 1)) * 72 + q * 8;
    float b4[2][4];
#pragma unroll
    for (int mi = 0; mi < 2; mi++)
#pragma unroll
      for (int r = 0; r < 4; r++) b4[mi][r] = db2[mi * 16 + q * 4 + r];
#pragma unroll
    for (int c = 0; c < 4; c++) {
      const int cy = c >> 1, cx = c & 1;
      floatx4 acc[2];
      acc[0] = (floatx4){0.f, 0.f, 0.f, 0.f};
      acc[1] = (floatx4){0.f, 0.f, 0.f, 0.f};
      for (int ks = 0; ks < 2; ks++) {
        uint4 af[2][4];
#pragma unroll
        for (int mi = 0; mi < 2; mi++)
#pragma unroll
          for (int tt = 0; tt < 4; tt++) {
            const int t2 = tt >> 1, t3 = tt & 1;
            const int ky = ((cy + 1) & 1) + 2 * t2, kx = ((cx + 1) & 1) + 2 * t3;
            af[mi][tt] = *reinterpret_cast<const uint4*>(
                wd2 + (size_t)((ky * 4 + kx) * 32 + mi * 16 + n) * 64 + ks * 32 + q * 8);
          }
#pragma unroll
        for (int tt = 0; tt < 4; tt++) {
          const int t2 = tt >> 1, t3 = tt & 1;
          const int toff = ((cy - t2) * 10 + (cx - t3)) * 72 + ks * 32;
          uint4 bf = *reinterpret_cast<const uint4*>(&sInD2[ibase + toff]);
#pragma unroll
          for (int mi = 0; mi < 2; mi++)
            acc[mi] = __builtin_amdgcn_mfma_f32_16x16x32_bf16(u2s(af[mi][tt]), u2s(bf),
                                                              acc[mi], 0, 0, 0);
        }
      }
      const int oy = 2 * Y + cy, ox = 2 * X + cx;
#pragma unroll
      for (int mi = 0; mi < 2; mi++) {
        const unsigned int lo =
            (unsigned int)f2h(fmaxf(acc[mi][0] + b4[mi][0], 0.f)) |
            ((unsigned int)f2h(fmaxf(acc[mi][1] + b4[mi][1], 0.f)) << 16);
        const unsigned int hi =
            (unsigned int)f2h(fmaxf(acc[mi][2] + b4[mi][2], 0.f)) |
            ((unsigned int)f2h(fmaxf(acc[mi][3] + b4[mi][3], 0.f)) << 16);
        *reinterpret_cast<uint2*>(&sInD3h[oy * D3_ROW + ox * D3_PX + mi * 16 + q * 4]) =
            make_uint2(lo, hi);
      }
    }
  }
  __syncthreads();
  // ---- deconv3 (f16 dot2 over ic, OC=1, sigmoid, REMAP) from sInD3h
  {
    const int oy = tid >> 3;               // 0..31
    const int rem2 = tid & 7;
    const int cpar = rem2 >> 2, qq = rem2 & 3;
    const int py = (oy + 1) & 1, pc = (cpar + 1) & 1;
    const int ixb0 = (cpar + 1 - pc) >> 1;
    const int xlo = ixb0 - 1 + qq * 4;
    float acc[4] = {0.f, 0.f, 0.f, 0.f};
    const float bv = b3[0];
#pragma unroll
    for (int u2 = 0; u2 < 2; u2++) {
      const int ky = py + 2 * u2;
      const int iy = (oy + 1 - ky) >> 1;
      if (iy < 0 || iy >= 16) continue;
      const _Float16* rowp = &sInD3h[iy * D3_ROW];
      const uint2* wAp = reinterpret_cast<const uint2*>(&sW3h[(ky * 4 + pc) * 32]);
      const uint2* wBp = reinterpret_cast<const uint2*>(&sW3h[(ky * 4 + pc + 2) * 32]);
#pragma unroll
      for (int kb = 0; kb < 8; kb++) {
        uint2 xv[5];
#pragma unroll
        for (int x = 0; x < 5; x++) {
          const int ix = xlo + x;
          xv[x] = (ix >= 0 && ix < 16)
              ? *reinterpret_cast<const uint2*>(&rowp[ix * D3_PX + kb * 4])
              : make_uint2(0u, 0u);
        }
        const uint2 wa = wAp[kb], wb = wBp[kb];
#pragma unroll
        for (int j = 0; j < 4; j++) {
          acc[j] = fdot2w(u2h(wa.x), u2h(xv[j + 1].x), acc[j]);
          acc[j] = fdot2w(u2h(wa.y), u2h(xv[j + 1].y), acc[j]);
          acc[j] = fdot2w(u2h(wb.x), u2h(xv[j].x), acc[j]);
          acc[j] = fdot2w(u2h(wb.y), u2h(xv[j].y), acc[j]);
        }
      }
    }
    const int fo = b * 64 + t;  // REMAP (t*32+b -> b*64+t)
    float* yf = out + (size_t)fo * 1024;
#pragma unroll
    for (int j = 0; j < 4; j++)
      yf[oy * 32 + (cpar + 2 * (qq * 4 + j))] = rcpf(1.f + __expf(-(acc[j] + bv)));
  }
}

// ==================== launch ====================
extern "C" void kernel_launch(void* const* d_in, const int* in_sizes, int n_in,
                              void* d_out, int out_size, void* d_ws, size_t ws_size,
                              hipStream_t stream) {
  const float* obs = (const float*)d_in[0];
  const float* actions = (const float*)d_in[1];
  const float* noise = (const float*)d_in[2];
  const float* enc_w1 = (const float*)d_in[3];
  const float* enc_b1 = (const float*)d_in[4];
  const float* enc_w2 = (const float*)d_in[5];
  const float* enc_b2 = (const float*)d_in[6];
  const float* enc_w3 = (const float*)d_in[7];
  const float* enc_b3 = (const float*)d_in[8];
  const float* enc_pw = (const float*)d_in[9];
  const float* enc_pb = (const float*)d_in[10];
  const float* dec_pw = (const float*)d_in[11];
  const float* dec_pb = (const float*)d_in[12];
  const float* dec_w1 = (const float*)d_in[13];
  const float* dec_b1 = (const float*)d_in[14];
  const float* dec_w2 = (const float*)d_in[15];
  const float* dec_b2 = (const float*)d_in[16];
  const float* dec_w3 = (const float*)d_in[17];
  const float* dec_b3 = (const float*)d_in[18];
  const float* gru_wih = (const float*)d_in[19];
  const float* gru_whh = (const float*)d_in[20];
  const float* gru_bih = (const float*)d_in[21];
  const float* gru_bhh = (const float*)d_in[22];
  const float* pri_w1 = (const float*)d_in[23];
  const float* pri_b1 = (const float*)d_in[24];
  const float* pri_w2 = (const float*)d_in[25];
  const float* pri_b2 = (const float*)d_in[26];
  const float* pri_w3 = (const float*)d_in[27];
  const float* pri_b3 = (const float*)d_in[28];
  const float* pos_w1 = (const float*)d_in[29];
  const float* pos_b1 = (const float*)d_in[30];
  const float* pos_w2 = (const float*)d_in[31];
  const float* pos_b2 = (const float*)d_in[32];
  const float* pos_w3 = (const float*)d_in[33];
  const float* pos_b3 = (const float*)d_in[34];

  float* out = (float*)d_out;
  float* ws = (float*)d_ws;
  float* HS = ws + WS_HS;
  float* POSL1E = ws + WS_POSL1E;
  float* GIA = ws + WS_GIA;
  unsigned short* WP1H = (unsigned short*)(ws + WS_WP1H);
  unsigned short* WP2 = (unsigned short*)(ws + WS_WP2);
  unsigned short* WP3 = (unsigned short*)(ws + WS_WP3);
  unsigned short* WWHH = (unsigned short*)(ws + WS_WWHH);
  unsigned short* WIHZ = (unsigned short*)(ws + WS_WIHZ);
  unsigned short* WC2 = (unsigned short*)(ws + WS_WC2);
  unsigned short* WC3 = (unsigned short*)(ws + WS_WC3);
  unsigned short* WD1 = (unsigned short*)(ws + WS_WD1);
  unsigned short* WD2 = (unsigned short*)(ws + WS_WD2);
  unsigned short* DLIN = (unsigned short*)(ws + WS_DLIN);
  unsigned short* DECWF = (unsigned short*)(ws + WS_DECWF);
  unsigned short* QW1F = (unsigned short*)(ws + WS_QW1F);
  unsigned short* QW2F = (unsigned short*)(ws + WS_QW2F);
  unsigned short* QW3F = (unsigned short*)(ws + WS_QW3F);
  unsigned short* ENCWF = (unsigned short*)(ws + WS_ENCWF);
  unsigned short* PW1E = (unsigned short*)(ws + WS_PW1E);
  unsigned short* XE = (unsigned short*)(ws + WS_XE);

  // unified prep
  PPAll pp;
  pp.m[0]  = {enc_pw, ENCWF, 64 * 1024, 0, 0, 0};
  pp.m[1]  = {dec_pw, DECWF, 1024 * 160, 0, 0, 0};
  pp.m[2]  = {pri_w1, QW1F, 128 * 160, 6, 0, 0};
  pp.m[3]  = {pri_w2, QW2F, 128 * 128, 0, 0, 0};
  pp.m[4]  = {pri_w3, QW3F, 64 * 128, 0, 0, 0};
  pp.m[5]  = {pos_w1, PW1E, 128 * 64, 7, 0, 0};
  pp.m[6]  = {gru_wih, ws + WS_WIHT, 384 * 34, 10, 384, 34};
  pp.m[7]  = {pos_w1, WP1H, 128 * 128, 1, 0, 0};
  pp.m[8]  = {pos_w2, WP2, 128 * 128, 0, 0, 0};
  pp.m[9]  = {pos_w3, WP3, 64 * 128, 0, 0, 0};
  pp.m[10] = {gru_whh, WWHH, 384 * 128, 0, 0, 0};
  pp.m[11] = {gru_wih, WIHZ, 384 * 32, 2, 0, 0};
  pp.m[12] = {enc_w2, WC2, 16 * 64 * 32, 3, 64, 32};
  pp.m[13] = {enc_w3, WC3, 16 * 64 * 64, 3, 64, 64};
  pp.m[14] = {dec_w1, WD1, 16 * 64 * 64, 4, 64, 64};
  pp.m[15] = {dec_w2, WD2, 16 * 32 * 64, 4, 32, 64};
  hipLaunchKernelGGL(k_prep, dim3(32, 16), dim3(256), 0, stream, pp);

  // fused encoder (conv1..conv3 -> XE) + gia
  k_enc<<<NF, 256, 0, stream>>>(obs, actions, enc_w1, enc_b1, WC2, enc_b2,
                                WC3, enc_b3, ws + WS_WIHT, gru_bih, gru_bhh,
                                XE, GIA);

  // embed + pos-L1 batched GEMM
  k_emb<<<128, 256, 0, stream>>>(XE, ENCWF, enc_pb, PW1E, pos_b1, POSL1E);

  // sequential core
  k_rssm4<<<NB, 512, 0, stream>>>(POSL1E, GIA, noise, WP1H, WP2, WP3, WWHH, WIHZ,
                                  pos_b2, pos_b3, HS, out);

  // declin GEMM + prior GEMM chain (single dispatch)
  k_post<<<2176, 256, 0, stream>>>(HS, out + OUT_ZS, DECWF, dec_pb, DLIN,
                                   actions, QW1F, pri_b1, QW2F, pri_b2,
                                   QW3F, pri_b3, out);

  // fused decoder (deconv1..deconv3)
  k_dec<<<NF, 256, 0, stream>>>(DLIN, WD1, dec_b1, WD2, dec_b2, dec_w3, dec_b3, out);
}